// Round 12
// baseline (1035.418 us; speedup 1.0000x reference)
//
#include <hip/hip_runtime.h>
#include <stdint.h>
#include <stddef.h>

typedef _Float16 f16;
typedef _Float16 f16x8 __attribute__((ext_vector_type(8)));
typedef float    f32x4 __attribute__((ext_vector_type(4)));

#define NB 8192  // total batch

struct Ptrs {
  const float *G0[5], *G1[5], *G2[5], *G3[5], *bias[5];
  float *T01[5], *T23[5], *biasr[5];
  f16   *WHt[5];
};

// job 0-4: T01[L];  job 5-9: T23[L];  job 10-14: bias rearrange
__global__ void prep1_kernel(Ptrs p) {
  constexpr int IM[5][5] = {{7,4,4,4,7},{8,8,8,8,4},{8,8,8,4,4},{8,8,4,4,4},{8,4,4,4,4}};
  constexpr int OM[5][5] = {{8,8,8,8,4},{8,8,8,4,4},{8,8,4,4,4},{8,4,4,4,4},{10,1,1,1,1}};
  const int job = blockIdx.x;
  const int tid = threadIdx.x;
  if (job < 5) {
    const int L = job;
    const int m1=IM[L][1], n0=OM[L][0], n1=OM[L][1];
    const int n01 = n0*n1;
    const int cnt = IM[L][0]*m1*n01*7;
    const float* G0 = p.G0[L]; const float* G1 = p.G1[L];
    float* T = p.T01[L];
    for (int e = tid; e < cnt; e += blockDim.x) {
      const int r2  = e % 7;
      const int j01 = (e/7) % n01;
      const int i01 = e / (7*n01);
      const int i0 = i01/m1, i1 = i01 - i0*m1;
      const int j0 = j01/n1, j1 = j01 - j0*n1;
      float s = 0.f;
      for (int r1 = 0; r1 < 7; ++r1)
        s += G0[(i0*n0 + j0)*7 + r1] * G1[((r1*m1 + i1)*n1 + j1)*7 + r2];
      T[e] = s;  // [i01][j01][r2]
    }
  } else if (job < 10) {
    const int L = job - 5;
    const int m2=IM[L][2], m3=IM[L][3], n2=OM[L][2], n3=OM[L][3];
    const int n23 = n2*n3;
    const int cnt = m2*m3*n23*7;
    const float* G2 = p.G2[L]; const float* G3 = p.G3[L];
    float* T = p.T23[L];
    for (int e = tid; e < cnt; e += blockDim.x) {
      const int r2  = e % 7;
      const int j23 = (e/7) % n23;
      const int i23 = e / (7*n23);
      const int i2 = i23/m3, i3 = i23 - i2*m3;
      const int j2 = j23/n3, j3 = j23 - j2*n3;
      float s = 0.f;
      for (int r3 = 0; r3 < 7; ++r3)
        s += G2[((r2*m2 + i2)*n2 + j2)*7 + r3] * G3[(r3*m3 + i3)*n3 + j3];
      T[e] = s;  // [i23][j23][r2]
    }
  } else {
    const int L = job - 10;
    constexpr int OUTF[5] = {16384, 8192, 4096, 2048, 10};
    constexpr int N4[5]   = {4,4,4,4,1};
    const int of = OUTF[L], n4 = N4[L], outH = of / n4;
    const float* b = p.bias[L];
    float* br = p.biasr[L];
    for (int e = tid; e < of; e += blockDim.x) {
      const int j4 = e / outH, jH = e - j4*outH;
      br[e] = b[jH*n4 + j4];   // biasr[j4][jH]
    }
  }
}

// WHt[L][jH][iH] = sum_r2 T01[i01][j01][r2] * T23[i23][j23][r2]   (fp16 out)
__global__ void prep2_kernel(Ptrs p) {
  constexpr int INH[5]  = {448, 4096, 2048, 1024, 512};
  constexpr int M23[5]  = {16, 64, 32, 16, 16};
  constexpr int N23[5]  = {64, 32, 16, 16, 1};
  constexpr int N01[5]  = {64, 64, 64, 32, 10};
  constexpr int BASE[6] = {0, 1835008, 10223616, 12320768, 12845056, 12850176};
  const int total = BASE[5];
  for (int e = blockIdx.x*blockDim.x + threadIdx.x; e < total;
       e += gridDim.x*blockDim.x) {
    int L = 0;
    while (L < 4 && e >= BASE[L+1]) ++L;
    const int le = e - BASE[L];
    const int iH = le % INH[L];
    const int jH = le / INH[L];
    const int i01 = iH / M23[L], i23 = iH - i01*M23[L];
    const int j01 = jH / N23[L], j23 = jH - j01*N23[L];
    const float* a = p.T01[L] + (i01*N01[L] + j01)*7;
    const float* b = p.T23[L] + (i23*N23[L] + j23)*7;
    float s = 0.f;
#pragma unroll
    for (int r = 0; r < 7; ++r) s += a[r]*b[r];
    p.WHt[L][le] = (f16)s;   // [jH][iH]  (B-transposed [N][K])
  }
}

// Stage A for layer 1: x f32 [BC,3136] viewed [b][iH(448)][i4(7)] -> u [4BC,448] f16
__global__ void stagea_x(const float* __restrict__ x, const float* __restrict__ g4,
                         f16* __restrict__ u, int BC) {
  const int idx = blockIdx.x*blockDim.x + threadIdx.x;
  if (idx >= BC*448) return;
  const int b = idx / 448, c = idx - b*448;
  const float* xr = x + (size_t)b*3136 + c*7;
  float v[7];
#pragma unroll
  for (int i = 0; i < 7; ++i) v[i] = xr[i];
#pragma unroll
  for (int j = 0; j < 4; ++j) {
    float s = 0.f;
#pragma unroll
    for (int i = 0; i < 7; ++i) s += v[i]*g4[i*4+j];
    u[(size_t)(b*4+j)*448 + c] = (f16)s;
  }
}

// ---------------------------------------------------------------------------
// 256x256-tile GEMM, 4 waves (2x2), per-wave 128x128, fused epilogue.
// Rationale (r11 post-mortem): with 8 waves, LDS fragment reads are 192 KB/tile
// (A 4x redundant) ~= the MFMA floor -> two co-critical pipes. 4 waves cut
// reads to 128 KB/tile (A 2x, B 2x); MFMA floor/SIMD unchanged (1 wave x 128).
// Schedule = round-10 proven: stage(next) -> read h1 frags -> MFMA h0 ->
// vmcnt(0) -> s_barrier (cross-wave DMA visibility) -> read h0 frags(next)
// -> MFMA h1. Both-sides XOR swizzle (0 conflicts). XCD-bijective grid.
__global__ void __launch_bounds__(256, 1)
gemm256(const f16* __restrict__ A, const f16* __restrict__ Bt,
        f16* __restrict__ U, const float* __restrict__ biasr,
        const float* __restrict__ g4n,
        int N, int K, int n4n)
{
  __shared__ f16 Ls[2][2][256*64];   // [buf][A/B][row 256][col 64] = 128 KB

  const int tid  = threadIdx.x;
  const int wid  = tid >> 6, lane = tid & 63;
  const int wr   = wid >> 1, wc = wid & 1;     // 2 x 2 wave grid
  const int l15  = lane & 15, l4 = lane >> 4, lm = l15 & 7;

  // ---- block swizzle: XCD-bijective + N-fastest ----
  const int nwg = gridDim.x;
  int wg = blockIdx.x;
  if ((nwg & 7) == 0) wg = (wg & 7) * (nwg >> 3) + (wg >> 3);
  const int Nt = N >> 8;
  const int bx = wg / Nt, by = wg - bx * Nt;
  const int m0 = bx << 8, n0 = by << 8;

  // ---- staging: 16 loads/thread/tile; round q covers rows q*32 + (tid>>3) ----
  const int rr   = tid >> 3;                       // 0..31
  const int cs8  = (((tid & 7) ^ (rr & 7)) << 3);  // swizzled source chunk (elems)
  const int dst0 = tid << 3;                       // linear LDS elem offset

  // ---- fragment-read offsets (swizzled, per-lane constant), per half h ----
  const int cz0 = ((l4 ^ lm)) << 3;
  const int cz1 = ((4 + l4) ^ lm) << 3;
  const int ax0 = ((wr << 7) + l15) * 64 + cz0;
  const int ax1 = ((wr << 7) + l15) * 64 + cz1;
  const int bx0 = ((wc << 7) + l15) * 64 + cz0;
  const int bx1 = ((wc << 7) + l15) * 64 + cz1;

  f32x4 acc[8][8] = {};
  f16x8 af0[8], bf0[8], af1[8], bf1[8];

  auto stage = [&](int buf, int kt) {
    const f16* gA = A + (size_t)m0 * K + kt;
    const f16* gB = Bt + (size_t)n0 * K + kt;
    f16* dA = &Ls[buf][0][0];
    f16* dB = &Ls[buf][1][0];
#pragma unroll
    for (int q = 0; q < 8; ++q)
      __builtin_amdgcn_global_load_lds(
          (const __attribute__((address_space(1))) void*)(gA + (size_t)(q*32 + rr)*K + cs8),
          (__attribute__((address_space(3))) void*)(dA + q*2048 + dst0), 16, 0, 0);
#pragma unroll
    for (int q = 0; q < 8; ++q)
      __builtin_amdgcn_global_load_lds(
          (const __attribute__((address_space(1))) void*)(gB + (size_t)(q*32 + rr)*K + cs8),
          (__attribute__((address_space(3))) void*)(dB + q*2048 + dst0), 16, 0, 0);
  };

  // ---- prologue: land buf0 (all waves), preload half-0 frags ----
  stage(0, 0);
  asm volatile("s_waitcnt vmcnt(0)" ::: "memory");
  __builtin_amdgcn_s_barrier();
#pragma unroll
  for (int n = 0; n < 8; ++n) bf0[n] = *(const f16x8*)(&Ls[0][1][0] + bx0 + n*1024);
#pragma unroll
  for (int m = 0; m < 8; ++m) af0[m] = *(const f16x8*)(&Ls[0][0][0] + ax0 + m*1024);

  const int nt = K >> 6;
  for (int t = 0; t < nt - 1; ++t) {
    const int cur = t & 1;
    stage(cur ^ 1, (t + 1) << 6);                 // 16 loads -> buf[cur^1]
    __builtin_amdgcn_sched_barrier(0);
    {
      const f16* As = &Ls[cur][0][0];
      const f16* Bs = &Ls[cur][1][0];
#pragma unroll
      for (int n = 0; n < 8; ++n) bf1[n] = *(const f16x8*)(Bs + bx1 + n*1024);
#pragma unroll
      for (int m = 0; m < 8; ++m) af1[m] = *(const f16x8*)(As + ax1 + m*1024);
    }
    __builtin_amdgcn_s_setprio(1);                // MFMA half-0 overlaps R1 reads + DMA
#pragma unroll
    for (int m = 0; m < 8; ++m)
#pragma unroll
      for (int n = 0; n < 8; ++n)
        acc[m][n] = __builtin_amdgcn_mfma_f32_16x16x32_f16(af0[m], bf0[n], acc[m][n], 0, 0, 0);
    __builtin_amdgcn_s_setprio(0);
    __builtin_amdgcn_sched_barrier(0);
    asm volatile("s_waitcnt vmcnt(0)" ::: "memory");   // my DMA drained (covered by MFMA h0)
    __builtin_amdgcn_s_barrier();                      // => ALL waves' DMA landed
    __builtin_amdgcn_sched_barrier(0);
    {
      const f16* As = &Ls[cur ^ 1][0][0];
      const f16* Bs = &Ls[cur ^ 1][1][0];
#pragma unroll
      for (int n = 0; n < 8; ++n) bf0[n] = *(const f16x8*)(Bs + bx0 + n*1024);
#pragma unroll
      for (int m = 0; m < 8; ++m) af0[m] = *(const f16x8*)(As + ax0 + m*1024);
    }
    __builtin_amdgcn_s_setprio(1);                // MFMA half-1 overlaps next R0 reads
#pragma unroll
    for (int m = 0; m < 8; ++m)
#pragma unroll
      for (int n = 0; n < 8; ++n)
        acc[m][n] = __builtin_amdgcn_mfma_f32_16x16x32_f16(af1[m], bf1[n], acc[m][n], 0, 0, 0);
    __builtin_amdgcn_s_setprio(0);
  }
  // ---- last tile: no stage, no gate ----
  {
    const int cur = (nt - 1) & 1;
    const f16* As = &Ls[cur][0][0];
    const f16* Bs = &Ls[cur][1][0];
#pragma unroll
    for (int n = 0; n < 8; ++n) bf1[n] = *(const f16x8*)(Bs + bx1 + n*1024);
#pragma unroll
    for (int m = 0; m < 8; ++m) af1[m] = *(const f16x8*)(As + ax1 + m*1024);
    __builtin_amdgcn_s_setprio(1);
#pragma unroll
    for (int m = 0; m < 8; ++m)
#pragma unroll
      for (int n = 0; n < 8; ++n)
        acc[m][n] = __builtin_amdgcn_mfma_f32_16x16x32_f16(af0[m], bf0[n], acc[m][n], 0, 0, 0);
#pragma unroll
    for (int m = 0; m < 8; ++m)
#pragma unroll
      for (int n = 0; n < 8; ++n)
        acc[m][n] = __builtin_amdgcn_mfma_f32_16x16x32_f16(af1[m], bf1[n], acc[m][n], 0, 0, 0);
    __builtin_amdgcn_s_setprio(0);
  }

  // ---- fused epilogue: bias + ReLU + next-layer g4 contraction ----
  // C/D frag: col = lane&15, row = (lane>>4)*4 + reg ; row base % 4 == 0
#pragma unroll
  for (int m = 0; m < 8; ++m) {
    const int rb = m0 + (wr << 7) + (m << 4) + (l4 << 2);  // multiple of 4
    const int b  = rb >> 2;                                // chunk-local batch idx
#pragma unroll
    for (int n = 0; n < 8; ++n) {
      const int col = n0 + (wc << 7) + (n << 4) + l15;
      float v[4];
#pragma unroll
      for (int r = 0; r < 4; ++r)
        v[r] = fmaxf(acc[m][n][r] + biasr[(size_t)r * N + col], 0.f);
      if (n4n == 4) {
#pragma unroll
        for (int j = 0; j < 4; ++j) {
          float s = v[0]*g4n[j] + v[1]*g4n[4+j] + v[2]*g4n[8+j] + v[3]*g4n[12+j];
          U[(size_t)(b*4 + j) * N + col] = (f16)s;
        }
      } else { // n4n == 1
        float s = v[0]*g4n[0] + v[1]*g4n[1] + v[2]*g4n[2] + v[3]*g4n[3];
        U[(size_t)b * N + col] = (f16)s;
      }
    }
  }
}

// ---------------------------------------------------------------------------
// 128x128-tile variant (kept for L4 where N=512 would underfill the grid at 256²).
__global__ void __launch_bounds__(256, 2)
gemm_fused(const f16* __restrict__ A, const f16* __restrict__ Bt,
           f16* __restrict__ U, const float* __restrict__ biasr,
           const float* __restrict__ g4n,
           int N, int K, int n4n)
{
  __shared__ f16 Ls[2][2][128*64];   // 64 KB

  const int tid  = threadIdx.x;
  const int wid  = tid >> 6, lane = tid & 63;
  const int wr   = wid >> 1, wc = wid & 1;
  const int l15  = lane & 15, l4 = lane >> 4, lm = l15 & 7;

  const int nwg = gridDim.x;
  int wg = blockIdx.x;
  if ((nwg & 7) == 0) wg = (wg & 7) * (nwg >> 3) + (wg >> 3);
  const int Nt = N >> 7;
  const int bx = wg / Nt, by = wg - bx * Nt;
  const int m0 = bx << 7, n0 = by << 7;

  const int rr   = tid >> 3;                       // 0..31
  const int cs8  = (((tid & 7) ^ (rr & 7)) << 3);
  const int dst0 = wid << 9;

  int axoff[2], bxoff[2];
#pragma unroll
  for (int h = 0; h < 2; ++h) {
    const int cz = (((h << 2) + l4) ^ lm) << 3;
    axoff[h] = ((wr << 6) + l15) * 64 + cz;
    bxoff[h] = ((wc << 6) + l15) * 64 + cz;
  }

  f32x4 acc[4][4] = {};

  auto stage = [&](int buf, int kt) {
    const f16* gA = A + (size_t)m0 * K + kt;
    const f16* gB = Bt + (size_t)n0 * K + kt;
    f16* dA = &Ls[buf][0][0];
    f16* dB = &Ls[buf][1][0];
#pragma unroll
    for (int q = 0; q < 4; ++q)
      __builtin_amdgcn_global_load_lds(
          (const __attribute__((address_space(1))) void*)(gA + (size_t)(q*32 + rr)*K + cs8),
          (__attribute__((address_space(3))) void*)(dA + q*2048 + dst0), 16, 0, 0);
#pragma unroll
    for (int q = 0; q < 4; ++q)
      __builtin_amdgcn_global_load_lds(
          (const __attribute__((address_space(1))) void*)(gB + (size_t)(q*32 + rr)*K + cs8),
          (__attribute__((address_space(3))) void*)(dB + q*2048 + dst0), 16, 0, 0);
  };

  stage(0, 0);
  __syncthreads();
  const int nt = K >> 6;
  int cur = 0;
  for (int t = 0; t < nt; ++t) {
    if (t + 1 < nt) stage(cur ^ 1, (t + 1) << 6);
    __builtin_amdgcn_sched_barrier(0);
    const f16* As = &Ls[cur][0][0];
    const f16* Bs = &Ls[cur][1][0];
#pragma unroll
    for (int h = 0; h < 2; ++h) {
      f16x8 af[4], bf[4];
#pragma unroll
      for (int n = 0; n < 4; ++n) bf[n] = *(const f16x8*)(Bs + bxoff[h] + n*1024);
#pragma unroll
      for (int m = 0; m < 4; ++m) af[m] = *(const f16x8*)(As + axoff[h] + m*1024);
      __builtin_amdgcn_s_setprio(1);
#pragma unroll
      for (int m = 0; m < 4; ++m)
#pragma unroll
        for (int n = 0; n < 4; ++n)
          acc[m][n] = __builtin_amdgcn_mfma_f32_16x16x32_f16(af[m], bf[n], acc[m][n], 0, 0, 0);
      __builtin_amdgcn_s_setprio(0);
    }
    __syncthreads();
    cur ^= 1;
  }

#pragma unroll
  for (int m = 0; m < 4; ++m) {
    const int rb = m0 + (wr << 6) + (m << 4) + (l4 << 2);
    const int b  = rb >> 2;
#pragma unroll
    for (int n = 0; n < 4; ++n) {
      const int col = n0 + (wc << 6) + (n << 4) + l15;
      float v[4];
#pragma unroll
      for (int r = 0; r < 4; ++r)
        v[r] = fmaxf(acc[m][n][r] + biasr[(size_t)r * N + col], 0.f);
      if (n4n == 4) {
#pragma unroll
        for (int j = 0; j < 4; ++j) {
          float s = v[0]*g4n[j] + v[1]*g4n[4+j] + v[2]*g4n[8+j] + v[3]*g4n[12+j];
          U[(size_t)(b*4 + j) * N + col] = (f16)s;
        }
      } else {
        float s = v[0]*g4n[0] + v[1]*g4n[1] + v[2]*g4n[2] + v[3]*g4n[3];
        U[(size_t)b * N + col] = (f16)s;
      }
    }
  }
}

// L5: logits[b,j] = sum_k u5[b,k]*WHt5[j,k] + bias[j] (j<10), softmax. 1 wave/row.
__global__ void l5_softmax(const f16* __restrict__ u, const f16* __restrict__ Wt,
                           const float* __restrict__ bias, float* __restrict__ out)
{
  const int wid = threadIdx.x >> 6, lane = threadIdx.x & 63;
  const int row = blockIdx.x*4 + wid;
  float acc[10] = {};
  const f16* ur = u + (size_t)row*512;
#pragma unroll
  for (int t = 0; t < 8; ++t) {
    const float a = (float)ur[t*64 + lane];
#pragma unroll
    for (int j = 0; j < 10; ++j)
      acc[j] += a * (float)Wt[j*512 + t*64 + lane];
  }
#pragma unroll
  for (int j = 0; j < 10; ++j) {
#pragma unroll
    for (int s = 32; s; s >>= 1) acc[j] += __shfl_xor(acc[j], s);
    acc[j] += bias[j];
  }
  float mx = acc[0];
#pragma unroll
  for (int j = 1; j < 10; ++j) mx = fmaxf(mx, acc[j]);
  float sum = 0.f;
#pragma unroll
  for (int j = 0; j < 10; ++j) { acc[j] = __expf(acc[j]-mx); sum += acc[j]; }
  const float inv = 1.f / sum;
  if (lane < 10) out[(size_t)row*10 + lane] = acc[lane]*inv;
}

// ---------------------------------------------------------------------------
extern "C" void kernel_launch(void* const* d_in, const int* in_sizes, int n_in,
                              void* d_out, int out_size, void* d_ws, size_t ws_size,
                              hipStream_t stream) {
  (void)in_sizes; (void)n_in; (void)out_size;
  const float* x = (const float*)d_in[0];
  Ptrs p;
  const float* G4[5];
  for (int L = 0; L < 5; ++L) {
    p.G0[L]   = (const float*)d_in[1 + L*6 + 0];
    p.G1[L]   = (const float*)d_in[1 + L*6 + 1];
    p.G2[L]   = (const float*)d_in[1 + L*6 + 2];
    p.G3[L]   = (const float*)d_in[1 + L*6 + 3];
    G4[L]     = (const float*)d_in[1 + L*6 + 4];
    p.bias[L] = (const float*)d_in[1 + L*6 + 5];
  }

  uintptr_t w = (uintptr_t)d_ws;
  auto alloc = [&](size_t bytes) {
    uintptr_t r = w; w += (bytes + 255) & ~(size_t)255; return (void*)r;
  };
  constexpr int  t01sz[5] = {12544, 28672, 28672, 14336, 2240};
  constexpr int  t23sz[5] = {7168, 14336, 3584, 1792, 112};
  constexpr int  brsz[5]  = {16384, 8192, 4096, 2048, 10};
  constexpr long whsz[5]  = {448L*4096, 4096L*2048, 2048L*1024, 1024L*512, 512L*10};
  for (int L = 0; L < 5; ++L) p.T01[L]   = (float*)alloc((size_t)t01sz[L]*4);
  for (int L = 0; L < 5; ++L) p.T23[L]   = (float*)alloc((size_t)t23sz[L]*4);
  for (int L = 0; L < 5; ++L) p.biasr[L] = (float*)alloc((size_t)brsz[L]*4);
  for (int L = 0; L < 5; ++L) p.WHt[L]   = (f16*)alloc((size_t)whsz[L]*2);
  const size_t fixedBytes = (size_t)(w - (uintptr_t)d_ws);

  // per-chunk ping-pong: bufA holds u1/u3/u5 (<=16KB/batch), bufB u2/u4 (<=32KB/batch)
  int BC = 0;
  for (int c = NB; c >= 64; c >>= 1)
    if (fixedBytes + (size_t)c * (16384 + 32768) <= ws_size) { BC = c; break; }
  if (!BC) return;  // workspace hopelessly small
  f16* bufA = (f16*)alloc((size_t)BC*16384);
  f16* bufB = (f16*)alloc((size_t)BC*32768);

  prep1_kernel<<<15, 256, 0, stream>>>(p);
  prep2_kernel<<<4096, 256, 0, stream>>>(p);

  const int nch = NB / BC;
  const int M   = BC * 4;
  for (int ch = 0; ch < nch; ++ch) {
    const size_t cs = (size_t)ch * BC;
    stagea_x<<<(BC*448 + 255)/256, 256, 0, stream>>>(x + cs*3136, G4[0], bufA, BC);
    // L1: u1[M,448] x WHt0 -> (bias,relu,g4_2) -> u2[M,4096]
    gemm256<<<(M/256)*(4096/256), 256, 0, stream>>>(bufA, p.WHt[0], bufB, p.biasr[0],
                                                    G4[1], 4096, 448, 4);
    // L2: u2 x WHt1 -> u3[M,2048]
    gemm256<<<(M/256)*(2048/256), 256, 0, stream>>>(bufB, p.WHt[1], bufA, p.biasr[1],
                                                    G4[2], 2048, 4096, 4);
    // L3: u3 x WHt2 -> u4[M,1024]
    gemm256<<<(M/256)*(1024/256), 256, 0, stream>>>(bufA, p.WHt[2], bufB, p.biasr[2],
                                                    G4[3], 1024, 2048, 4);
    // L4: u4 x WHt3 -> u5[BC,512] (n4n=1)  -- 128² kernel (grid 4x wider at N=512)
    gemm_fused<<<(M/128)*(512/128), 256, 0, stream>>>(bufB, p.WHt[3], bufA, p.biasr[3],
                                                      G4[4], 512, 1024, 1);
    // L5 + softmax
    l5_softmax<<<BC/4, 256, 0, stream>>>(bufA, p.WHt[4], p.biasr[4],
                                         (float*)d_out + cs*10);
  }
}

// Round 13
// 940.592 us; speedup vs baseline: 1.1008x; 1.1008x over previous
//
#include <hip/hip_runtime.h>
#include <stdint.h>
#include <stddef.h>

typedef _Float16 f16;
typedef _Float16 f16x8 __attribute__((ext_vector_type(8)));
typedef float    f32x4 __attribute__((ext_vector_type(4)));

#define NB 8192  // total batch

struct Ptrs {
  const float *G0[5], *G1[5], *G2[5], *G3[5], *bias[5];
  float *T01[5], *T23[5], *biasr[5];
  f16   *WHt[5];
};

// job 0-4: T01[L];  job 5-9: T23[L];  job 10-14: bias rearrange
__global__ void prep1_kernel(Ptrs p) {
  constexpr int IM[5][5] = {{7,4,4,4,7},{8,8,8,8,4},{8,8,8,4,4},{8,8,4,4,4},{8,4,4,4,4}};
  constexpr int OM[5][5] = {{8,8,8,8,4},{8,8,8,4,4},{8,8,4,4,4},{8,4,4,4,4},{10,1,1,1,1}};
  const int job = blockIdx.x;
  const int tid = threadIdx.x;
  if (job < 5) {
    const int L = job;
    const int m1=IM[L][1], n0=OM[L][0], n1=OM[L][1];
    const int n01 = n0*n1;
    const int cnt = IM[L][0]*m1*n01*7;
    const float* G0 = p.G0[L]; const float* G1 = p.G1[L];
    float* T = p.T01[L];
    for (int e = tid; e < cnt; e += blockDim.x) {
      const int r2  = e % 7;
      const int j01 = (e/7) % n01;
      const int i01 = e / (7*n01);
      const int i0 = i01/m1, i1 = i01 - i0*m1;
      const int j0 = j01/n1, j1 = j01 - j0*n1;
      float s = 0.f;
      for (int r1 = 0; r1 < 7; ++r1)
        s += G0[(i0*n0 + j0)*7 + r1] * G1[((r1*m1 + i1)*n1 + j1)*7 + r2];
      T[e] = s;  // [i01][j01][r2]
    }
  } else if (job < 10) {
    const int L = job - 5;
    const int m2=IM[L][2], m3=IM[L][3], n2=OM[L][2], n3=OM[L][3];
    const int n23 = n2*n3;
    const int cnt = m2*m3*n23*7;
    const float* G2 = p.G2[L]; const float* G3 = p.G3[L];
    float* T = p.T23[L];
    for (int e = tid; e < cnt; e += blockDim.x) {
      const int r2  = e % 7;
      const int j23 = (e/7) % n23;
      const int i23 = e / (7*n23);
      const int i2 = i23/m3, i3 = i23 - i2*m3;
      const int j2 = j23/n3, j3 = j23 - j2*n3;
      float s = 0.f;
      for (int r3 = 0; r3 < 7; ++r3)
        s += G2[((r2*m2 + i2)*n2 + j2)*7 + r3] * G3[(r3*m3 + i3)*n3 + j3];
      T[e] = s;  // [i23][j23][r2]
    }
  } else {
    const int L = job - 10;
    constexpr int OUTF[5] = {16384, 8192, 4096, 2048, 10};
    constexpr int N4[5]   = {4,4,4,4,1};
    const int of = OUTF[L], n4 = N4[L], outH = of / n4;
    const float* b = p.bias[L];
    float* br = p.biasr[L];
    for (int e = tid; e < of; e += blockDim.x) {
      const int j4 = e / outH, jH = e - j4*outH;
      br[e] = b[jH*n4 + j4];   // biasr[j4][jH]
    }
  }
}

// WHt[L][jH][iH] = sum_r2 T01[i01][j01][r2] * T23[i23][j23][r2]   (fp16 out)
__global__ void prep2_kernel(Ptrs p) {
  constexpr int INH[5]  = {448, 4096, 2048, 1024, 512};
  constexpr int M23[5]  = {16, 64, 32, 16, 16};
  constexpr int N23[5]  = {64, 32, 16, 16, 1};
  constexpr int N01[5]  = {64, 64, 64, 32, 10};
  constexpr int BASE[6] = {0, 1835008, 10223616, 12320768, 12845056, 12850176};
  const int total = BASE[5];
  for (int e = blockIdx.x*blockDim.x + threadIdx.x; e < total;
       e += gridDim.x*blockDim.x) {
    int L = 0;
    while (L < 4 && e >= BASE[L+1]) ++L;
    const int le = e - BASE[L];
    const int iH = le % INH[L];
    const int jH = le / INH[L];
    const int i01 = iH / M23[L], i23 = iH - i01*M23[L];
    const int j01 = jH / N23[L], j23 = jH - j01*N23[L];
    const float* a = p.T01[L] + (i01*N01[L] + j01)*7;
    const float* b = p.T23[L] + (i23*N23[L] + j23)*7;
    float s = 0.f;
#pragma unroll
    for (int r = 0; r < 7; ++r) s += a[r]*b[r];
    p.WHt[L][le] = (f16)s;   // [jH][iH]  (B-transposed [N][K])
  }
}

// Stage A for layer 1: x f32 [BC,3136] viewed [b][iH(448)][i4(7)] -> u [4BC,448] f16
__global__ void stagea_x(const float* __restrict__ x, const float* __restrict__ g4,
                         f16* __restrict__ u, int BC) {
  const int idx = blockIdx.x*blockDim.x + threadIdx.x;
  if (idx >= BC*448) return;
  const int b = idx / 448, c = idx - b*448;
  const float* xr = x + (size_t)b*3136 + c*7;
  float v[7];
#pragma unroll
  for (int i = 0; i < 7; ++i) v[i] = xr[i];
#pragma unroll
  for (int j = 0; j < 4; ++j) {
    float s = 0.f;
#pragma unroll
    for (int i = 0; i < 7; ++i) s += v[i]*g4[i*4+j];
    u[(size_t)(b*4+j)*448 + c] = (f16)s;
  }
}

// ---------------------------------------------------------------------------
// 256x256-tile GEMM, 8 waves (2x4), per-wave 128x64, fused epilogue.
// Round-10 schedule (best measured) + sched_barrier(0) AFTER each fragment
// read block: r10's VGPR_Count=128 (= acc alone) implies the compiler sank
// the frag reads down to their MFMA-h1 use, defeating the intended
// read/MFMA overlap. Pinning reads before the following MFMA cluster makes
// the overlap real. Cross-wave DMA visibility: wave drains own DMA (vmcnt)
// THEN s_barrier. Both-sides XOR swizzle (0 conflicts). XCD-bijective grid.
__global__ void __launch_bounds__(512, 2)
gemm256(const f16* __restrict__ A, const f16* __restrict__ Bt,
        f16* __restrict__ U, const float* __restrict__ biasr,
        const float* __restrict__ g4n,
        int N, int K, int n4n)
{
  __shared__ f16 Ls[2][2][256*64];   // [buf][A/B][row 256][col 64] = 128 KB

  const int tid  = threadIdx.x;
  const int wid  = tid >> 6, lane = tid & 63;
  const int wr   = wid >> 2, wc = wid & 3;     // 2 x 4 wave grid
  const int l15  = lane & 15, l4 = lane >> 4, lm = l15 & 7;

  // ---- block swizzle: XCD-bijective + N-fastest ----
  const int nwg = gridDim.x;
  int wg = blockIdx.x;
  if ((nwg & 7) == 0) wg = (wg & 7) * (nwg >> 3) + (wg >> 3);
  const int Nt = N >> 8;
  const int bx = wg / Nt, by = wg - bx * Nt;
  const int m0 = bx << 8, n0 = by << 8;

  // ---- staging constants: round q covers rows q*64 + (tid>>3), chunk tid&7 ----
  const int rr   = tid >> 3;                       // 0..63
  const int cs8  = (((tid & 7) ^ (rr & 7)) << 3);  // swizzled source chunk (elems)
  const int dst0 = tid << 3;                       // linear LDS elem offset

  // ---- fragment-read offsets (swizzled, per-lane constant), per half h ----
  const int cz0 = ((l4 ^ lm)) << 3;
  const int cz1 = ((4 + l4) ^ lm) << 3;
  const int ax0 = ((wr << 7) + l15) * 64 + cz0;
  const int ax1 = ((wr << 7) + l15) * 64 + cz1;
  const int bx0 = ((wc << 6) + l15) * 64 + cz0;
  const int bx1 = ((wc << 6) + l15) * 64 + cz1;

  f32x4 acc[8][4] = {};
  f16x8 af0[8], bf0[4], af1[8], bf1[4];

  auto stage = [&](int buf, int kt) {
    const f16* gA = A + (size_t)m0 * K + kt;
    const f16* gB = Bt + (size_t)n0 * K + kt;
    f16* dA = &Ls[buf][0][0];
    f16* dB = &Ls[buf][1][0];
#pragma unroll
    for (int q = 0; q < 4; ++q)
      __builtin_amdgcn_global_load_lds(
          (const __attribute__((address_space(1))) void*)(gA + (size_t)(q*64 + rr)*K + cs8),
          (__attribute__((address_space(3))) void*)(dA + q*4096 + dst0), 16, 0, 0);
#pragma unroll
    for (int q = 0; q < 4; ++q)
      __builtin_amdgcn_global_load_lds(
          (const __attribute__((address_space(1))) void*)(gB + (size_t)(q*64 + rr)*K + cs8),
          (__attribute__((address_space(3))) void*)(dB + q*4096 + dst0), 16, 0, 0);
  };

  // ---- prologue: land buf0 (all waves), preload half-0 frags ----
  stage(0, 0);
  asm volatile("s_waitcnt vmcnt(0)" ::: "memory");
  __builtin_amdgcn_s_barrier();
#pragma unroll
  for (int n = 0; n < 4; ++n) bf0[n] = *(const f16x8*)(&Ls[0][1][0] + bx0 + n*1024);
#pragma unroll
  for (int m = 0; m < 8; ++m) af0[m] = *(const f16x8*)(&Ls[0][0][0] + ax0 + m*1024);

  const int nt = K >> 6;
  for (int t = 0; t < nt - 1; ++t) {
    const int cur = t & 1;
    stage(cur ^ 1, (t + 1) << 6);                 // 8 loads -> buf[cur^1]
    __builtin_amdgcn_sched_barrier(0);
    {
      const f16* As = &Ls[cur][0][0];
      const f16* Bs = &Ls[cur][1][0];
#pragma unroll
      for (int n = 0; n < 4; ++n) bf1[n] = *(const f16x8*)(Bs + bx1 + n*1024);
#pragma unroll
      for (int m = 0; m < 8; ++m) af1[m] = *(const f16x8*)(As + ax1 + m*1024);
    }
    __builtin_amdgcn_sched_barrier(0);            // PIN reads BEFORE MFMA h0 (r12 dx)
    __builtin_amdgcn_s_setprio(1);                // MFMA half-0 overlaps R1 reads + DMA
#pragma unroll
    for (int m = 0; m < 8; ++m)
#pragma unroll
      for (int n = 0; n < 4; ++n)
        acc[m][n] = __builtin_amdgcn_mfma_f32_16x16x32_f16(af0[m], bf0[n], acc[m][n], 0, 0, 0);
    __builtin_amdgcn_s_setprio(0);
    __builtin_amdgcn_sched_barrier(0);
    asm volatile("s_waitcnt vmcnt(0)" ::: "memory");   // my DMA drained (covered by MFMA h0)
    __builtin_amdgcn_s_barrier();                      // => ALL waves' DMA landed
    __builtin_amdgcn_sched_barrier(0);
    {
      const f16* As = &Ls[cur ^ 1][0][0];
      const f16* Bs = &Ls[cur ^ 1][1][0];
#pragma unroll
      for (int n = 0; n < 4; ++n) bf0[n] = *(const f16x8*)(Bs + bx0 + n*1024);
#pragma unroll
      for (int m = 0; m < 8; ++m) af0[m] = *(const f16x8*)(As + ax0 + m*1024);
    }
    __builtin_amdgcn_sched_barrier(0);            // PIN reads BEFORE MFMA h1 (r12 dx)
    __builtin_amdgcn_s_setprio(1);                // MFMA half-1 overlaps next R0 reads
#pragma unroll
    for (int m = 0; m < 8; ++m)
#pragma unroll
      for (int n = 0; n < 4; ++n)
        acc[m][n] = __builtin_amdgcn_mfma_f32_16x16x32_f16(af1[m], bf1[n], acc[m][n], 0, 0, 0);
    __builtin_amdgcn_s_setprio(0);
  }
  // ---- last tile: no stage, no gate ----
  {
    const int cur = (nt - 1) & 1;
    const f16* As = &Ls[cur][0][0];
    const f16* Bs = &Ls[cur][1][0];
#pragma unroll
    for (int n = 0; n < 4; ++n) bf1[n] = *(const f16x8*)(Bs + bx1 + n*1024);
#pragma unroll
    for (int m = 0; m < 8; ++m) af1[m] = *(const f16x8*)(As + ax1 + m*1024);
    __builtin_amdgcn_s_setprio(1);
#pragma unroll
    for (int m = 0; m < 8; ++m)
#pragma unroll
      for (int n = 0; n < 4; ++n)
        acc[m][n] = __builtin_amdgcn_mfma_f32_16x16x32_f16(af0[m], bf0[n], acc[m][n], 0, 0, 0);
#pragma unroll
    for (int m = 0; m < 8; ++m)
#pragma unroll
      for (int n = 0; n < 4; ++n)
        acc[m][n] = __builtin_amdgcn_mfma_f32_16x16x32_f16(af1[m], bf1[n], acc[m][n], 0, 0, 0);
    __builtin_amdgcn_s_setprio(0);
  }

  // ---- fused epilogue: bias + ReLU + next-layer g4 contraction ----
  // C/D frag: col = lane&15, row = (lane>>4)*4 + reg ; row base % 4 == 0
#pragma unroll
  for (int m = 0; m < 8; ++m) {
    const int rb = m0 + (wr << 7) + (m << 4) + (l4 << 2);  // multiple of 4
    const int b  = rb >> 2;                                // chunk-local batch idx
#pragma unroll
    for (int n = 0; n < 4; ++n) {
      const int col = n0 + (wc << 6) + (n << 4) + l15;
      float v[4];
#pragma unroll
      for (int r = 0; r < 4; ++r)
        v[r] = fmaxf(acc[m][n][r] + biasr[(size_t)r * N + col], 0.f);
      if (n4n == 4) {
#pragma unroll
        for (int j = 0; j < 4; ++j) {
          float s = v[0]*g4n[j] + v[1]*g4n[4+j] + v[2]*g4n[8+j] + v[3]*g4n[12+j];
          U[(size_t)(b*4 + j) * N + col] = (f16)s;
        }
      } else { // n4n == 1
        float s = v[0]*g4n[0] + v[1]*g4n[1] + v[2]*g4n[2] + v[3]*g4n[3];
        U[(size_t)b * N + col] = (f16)s;
      }
    }
  }
}

// ---------------------------------------------------------------------------
// 128x128-tile variant (kept for L4 where N=512 would underfill the grid at 256²).
__global__ void __launch_bounds__(256, 2)
gemm_fused(const f16* __restrict__ A, const f16* __restrict__ Bt,
           f16* __restrict__ U, const float* __restrict__ biasr,
           const float* __restrict__ g4n,
           int N, int K, int n4n)
{
  __shared__ f16 Ls[2][2][128*64];   // 64 KB

  const int tid  = threadIdx.x;
  const int wid  = tid >> 6, lane = tid & 63;
  const int wr   = wid >> 1, wc = wid & 1;
  const int l15  = lane & 15, l4 = lane >> 4, lm = l15 & 7;

  const int nwg = gridDim.x;
  int wg = blockIdx.x;
  if ((nwg & 7) == 0) wg = (wg & 7) * (nwg >> 3) + (wg >> 3);
  const int Nt = N >> 7;
  const int bx = wg / Nt, by = wg - bx * Nt;
  const int m0 = bx << 7, n0 = by << 7;

  const int rr   = tid >> 3;                       // 0..31
  const int cs8  = (((tid & 7) ^ (rr & 7)) << 3);
  const int dst0 = wid << 9;

  int axoff[2], bxoff[2];
#pragma unroll
  for (int h = 0; h < 2; ++h) {
    const int cz = (((h << 2) + l4) ^ lm) << 3;
    axoff[h] = ((wr << 6) + l15) * 64 + cz;
    bxoff[h] = ((wc << 6) + l15) * 64 + cz;
  }

  f32x4 acc[4][4] = {};

  auto stage = [&](int buf, int kt) {
    const f16* gA = A + (size_t)m0 * K + kt;
    const f16* gB = Bt + (size_t)n0 * K + kt;
    f16* dA = &Ls[buf][0][0];
    f16* dB = &Ls[buf][1][0];
#pragma unroll
    for (int q = 0; q < 4; ++q)
      __builtin_amdgcn_global_load_lds(
          (const __attribute__((address_space(1))) void*)(gA + (size_t)(q*32 + rr)*K + cs8),
          (__attribute__((address_space(3))) void*)(dA + q*2048 + dst0), 16, 0, 0);
#pragma unroll
    for (int q = 0; q < 4; ++q)
      __builtin_amdgcn_global_load_lds(
          (const __attribute__((address_space(1))) void*)(gB + (size_t)(q*32 + rr)*K + cs8),
          (__attribute__((address_space(3))) void*)(dB + q*2048 + dst0), 16, 0, 0);
  };

  stage(0, 0);
  __syncthreads();
  const int nt = K >> 6;
  int cur = 0;
  for (int t = 0; t < nt; ++t) {
    if (t + 1 < nt) stage(cur ^ 1, (t + 1) << 6);
    __builtin_amdgcn_sched_barrier(0);
    const f16* As = &Ls[cur][0][0];
    const f16* Bs = &Ls[cur][1][0];
#pragma unroll
    for (int h = 0; h < 2; ++h) {
      f16x8 af[4], bf[4];
#pragma unroll
      for (int n = 0; n < 4; ++n) bf[n] = *(const f16x8*)(Bs + bxoff[h] + n*1024);
#pragma unroll
      for (int m = 0; m < 4; ++m) af[m] = *(const f16x8*)(As + axoff[h] + m*1024);
      __builtin_amdgcn_s_setprio(1);
#pragma unroll
      for (int m = 0; m < 4; ++m)
#pragma unroll
        for (int n = 0; n < 4; ++n)
          acc[m][n] = __builtin_amdgcn_mfma_f32_16x16x32_f16(af[m], bf[n], acc[m][n], 0, 0, 0);
      __builtin_amdgcn_s_setprio(0);
    }
    __syncthreads();
    cur ^= 1;
  }

#pragma unroll
  for (int m = 0; m < 4; ++m) {
    const int rb = m0 + (wr << 6) + (m << 4) + (l4 << 2);
    const int b  = rb >> 2;
#pragma unroll
    for (int n = 0; n < 4; ++n) {
      const int col = n0 + (wc << 6) + (n << 4) + l15;
      float v[4];
#pragma unroll
      for (int r = 0; r < 4; ++r)
        v[r] = fmaxf(acc[m][n][r] + biasr[(size_t)r * N + col], 0.f);
      if (n4n == 4) {
#pragma unroll
        for (int j = 0; j < 4; ++j) {
          float s = v[0]*g4n[j] + v[1]*g4n[4+j] + v[2]*g4n[8+j] + v[3]*g4n[12+j];
          U[(size_t)(b*4 + j) * N + col] = (f16)s;
        }
      } else {
        float s = v[0]*g4n[0] + v[1]*g4n[1] + v[2]*g4n[2] + v[3]*g4n[3];
        U[(size_t)b * N + col] = (f16)s;
      }
    }
  }
}

// L5: logits[b,j] = sum_k u5[b,k]*WHt5[j,k] + bias[j] (j<10), softmax. 1 wave/row.
__global__ void l5_softmax(const f16* __restrict__ u, const f16* __restrict__ Wt,
                           const float* __restrict__ bias, float* __restrict__ out)
{
  const int wid = threadIdx.x >> 6, lane = threadIdx.x & 63;
  const int row = blockIdx.x*4 + wid;
  float acc[10] = {};
  const f16* ur = u + (size_t)row*512;
#pragma unroll
  for (int t = 0; t < 8; ++t) {
    const float a = (float)ur[t*64 + lane];
#pragma unroll
    for (int j = 0; j < 10; ++j)
      acc[j] += a * (float)Wt[j*512 + t*64 + lane];
  }
#pragma unroll
  for (int j = 0; j < 10; ++j) {
#pragma unroll
    for (int s = 32; s; s >>= 1) acc[j] += __shfl_xor(acc[j], s);
    acc[j] += bias[j];
  }
  float mx = acc[0];
#pragma unroll
  for (int j = 1; j < 10; ++j) mx = fmaxf(mx, acc[j]);
  float sum = 0.f;
#pragma unroll
  for (int j = 0; j < 10; ++j) { acc[j] = __expf(acc[j]-mx); sum += acc[j]; }
  const float inv = 1.f / sum;
  if (lane < 10) out[(size_t)row*10 + lane] = acc[lane]*inv;
}

// ---------------------------------------------------------------------------
extern "C" void kernel_launch(void* const* d_in, const int* in_sizes, int n_in,
                              void* d_out, int out_size, void* d_ws, size_t ws_size,
                              hipStream_t stream) {
  (void)in_sizes; (void)n_in; (void)out_size;
  const float* x = (const float*)d_in[0];
  Ptrs p;
  const float* G4[5];
  for (int L = 0; L < 5; ++L) {
    p.G0[L]   = (const float*)d_in[1 + L*6 + 0];
    p.G1[L]   = (const float*)d_in[1 + L*6 + 1];
    p.G2[L]   = (const float*)d_in[1 + L*6 + 2];
    p.G3[L]   = (const float*)d_in[1 + L*6 + 3];
    G4[L]     = (const float*)d_in[1 + L*6 + 4];
    p.bias[L] = (const float*)d_in[1 + L*6 + 5];
  }

  uintptr_t w = (uintptr_t)d_ws;
  auto alloc = [&](size_t bytes) {
    uintptr_t r = w; w += (bytes + 255) & ~(size_t)255; return (void*)r;
  };
  constexpr int  t01sz[5] = {12544, 28672, 28672, 14336, 2240};
  constexpr int  t23sz[5] = {7168, 14336, 3584, 1792, 112};
  constexpr int  brsz[5]  = {16384, 8192, 4096, 2048, 10};
  constexpr long whsz[5]  = {448L*4096, 4096L*2048, 2048L*1024, 1024L*512, 512L*10};
  for (int L = 0; L < 5; ++L) p.T01[L]   = (float*)alloc((size_t)t01sz[L]*4);
  for (int L = 0; L < 5; ++L) p.T23[L]   = (float*)alloc((size_t)t23sz[L]*4);
  for (int L = 0; L < 5; ++L) p.biasr[L] = (float*)alloc((size_t)brsz[L]*4);
  for (int L = 0; L < 5; ++L) p.WHt[L]   = (f16*)alloc((size_t)whsz[L]*2);
  const size_t fixedBytes = (size_t)(w - (uintptr_t)d_ws);

  // per-chunk ping-pong: bufA holds u1/u3/u5 (<=16KB/batch), bufB u2/u4 (<=32KB/batch)
  int BC = 0;
  for (int c = NB; c >= 64; c >>= 1)
    if (fixedBytes + (size_t)c * (16384 + 32768) <= ws_size) { BC = c; break; }
  if (!BC) return;  // workspace hopelessly small
  f16* bufA = (f16*)alloc((size_t)BC*16384);
  f16* bufB = (f16*)alloc((size_t)BC*32768);

  prep1_kernel<<<15, 256, 0, stream>>>(p);
  prep2_kernel<<<4096, 256, 0, stream>>>(p);

  const int nch = NB / BC;
  const int M   = BC * 4;
  for (int ch = 0; ch < nch; ++ch) {
    const size_t cs = (size_t)ch * BC;
    stagea_x<<<(BC*448 + 255)/256, 256, 0, stream>>>(x + cs*3136, G4[0], bufA, BC);
    // L1: u1[M,448] x WHt0 -> (bias,relu,g4_2) -> u2[M,4096]
    gemm256<<<(M/256)*(4096/256), 512, 0, stream>>>(bufA, p.WHt[0], bufB, p.biasr[0],
                                                    G4[1], 4096, 448, 4);
    // L2: u2 x WHt1 -> u3[M,2048]
    gemm256<<<(M/256)*(2048/256), 512, 0, stream>>>(bufB, p.WHt[1], bufA, p.biasr[1],
                                                    G4[2], 2048, 4096, 4);
    // L3: u3 x WHt2 -> u4[M,1024]
    gemm256<<<(M/256)*(1024/256), 512, 0, stream>>>(bufA, p.WHt[2], bufB, p.biasr[2],
                                                    G4[3], 1024, 2048, 4);
    // L4: u4 x WHt3 -> u5[BC,512] (n4n=1)  -- 128² kernel (grid 4x wider at N=512)
    gemm_fused<<<(M/128)*(512/128), 256, 0, stream>>>(bufB, p.WHt[3], bufA, p.biasr[3],
                                                      G4[4], 512, 1024, 1);
    // L5 + softmax
    l5_softmax<<<BC/4, 256, 0, stream>>>(bufA, p.WHt[4], p.biasr[4],
                                         (float*)d_out + cs*10);
  }
}